// Round 3
// baseline (252.433 us; speedup 1.0000x reference)
//
#include <hip/hip_runtime.h>

typedef __bf16 bf16;
typedef __attribute__((ext_vector_type(8))) __bf16 bf16x8;
typedef __attribute__((ext_vector_type(4))) float floatx4;

#define TOK 2048
#define DD  1024
#define NE  8
#define S1MAX 40   // mlp1 slots (BM=128): <=23 routed + 16 shared, padded to %8==0
#define S2MAX 40   // mlp2 slots (BM=128): same bound, padded to %8==0

#define MFMA16(A,B,C) __builtin_amdgcn_mfma_f32_16x16x32_bf16(A,B,C,0,0,0)

__device__ __forceinline__ void load_lds16(const bf16* g, bf16* l) {
  __builtin_amdgcn_global_load_lds(
      (const __attribute__((address_space(1))) void*)g,
      (__attribute__((address_space(3))) void*)l, 16, 0, 0);
}

// fine-grained barrier: wait only the OLDEST outstanding loads, keep N in flight
#define WBAR(N) asm volatile("s_waitcnt vmcnt(" #N ")\n\ts_barrier" ::: "memory")
#define BARO    asm volatile("s_barrier" ::: "memory")

__device__ __forceinline__ uint4 pack_bf8(float4 a, float4 b) {
  union { bf16 h[8]; uint4 u; } p;
  p.h[0] = (bf16)a.x; p.h[1] = (bf16)a.y; p.h[2] = (bf16)a.z; p.h[3] = (bf16)a.w;
  p.h[4] = (bf16)b.x; p.h[5] = (bf16)b.y; p.h[6] = (bf16)b.z; p.h[7] = (bf16)b.w;
  return p.u;
}

// ---------------- weight fp32 -> bf16 conversion (W1/W3 row-interleaved) ----------------
#define NCVT (8*2046 + 2046 + 8*1023 + 1023)
__global__ __launch_bounds__(128) void convert_kernel(
    const float* __restrict__ W1, const float* __restrict__ W3,
    const float* __restrict__ W2, const float* __restrict__ Ws1,
    const float* __restrict__ Ws3, const float* __restrict__ Ws2,
    bf16* __restrict__ w13, bf16* __restrict__ ws13,
    bf16* __restrict__ w2b, bf16* __restrict__ ws2b)
{
  const int r = blockIdx.x, tid = threadIdx.x;
  const float* src; bf16* dst;
  if (r < 8 * 2046) {
    const int e = r / 2046, q = r % 2046;
    src = ((q & 1) ? W3 : W1) + ((size_t)e * 1023 + (q >> 1)) * 1024;
    dst = w13 + (size_t)r * 1024;
  } else if (r < 8 * 2046 + 2046) {
    const int q = r - 8 * 2046;
    src = ((q & 1) ? Ws3 : Ws1) + (size_t)(q >> 1) * 1024;
    dst = ws13 + (size_t)q * 1024;
  } else if (r < 8 * 2046 + 2046 + 8 * 1023) {
    const int q = r - (8 * 2046 + 2046);
    src = W2 + (size_t)q * 1024;
    dst = w2b + (size_t)q * 1024;
  } else {
    const int q = r - (8 * 2046 + 2046 + 8 * 1023);
    src = Ws2 + (size_t)q * 1024;
    dst = ws2b + (size_t)q * 1024;
  }
  const float4 f0 = ((const float4*)src)[tid * 2];
  const float4 f1 = ((const float4*)src)[tid * 2 + 1];
  ((uint4*)dst)[tid] = pack_bf8(f0, f1);
}

// ---------------- gate + x->bf16 + ss zero-init ----------------
__global__ __launch_bounds__(256) void gate_cvt_kernel(
    const float* __restrict__ x, const float* __restrict__ gate_w,
    const float* __restrict__ gate_b, bf16* __restrict__ x_bf,
    int* __restrict__ eidx, float* __restrict__ ewgt, float* __restrict__ ss)
{
  const int t = blockIdx.x, tid = threadIdx.x;
  if (tid < 4) ss[tid * TOK + t] = 0.f;
  const float4 v = ((const float4*)(x + (size_t)t * DD))[tid];
  union { bf16 h[4]; uint2 u; } pk;
  pk.h[0] = (bf16)v.x; pk.h[1] = (bf16)v.y; pk.h[2] = (bf16)v.z; pk.h[3] = (bf16)v.w;
  ((uint2*)(x_bf + (size_t)t * DD))[tid] = pk.u;

  float acc[NE];
#pragma unroll
  for (int e = 0; e < NE; ++e) acc[e] = 0.f;
  const float vv[4] = {v.x, v.y, v.z, v.w};
#pragma unroll
  for (int i = 0; i < 4; ++i) {
    const int d = tid * 4 + i;
    if (d >= 1) {
#pragma unroll
      for (int e = 0; e < NE; ++e) acc[e] += vv[i] * gate_w[e * (DD - 1) + d - 1];
    }
  }
#pragma unroll
  for (int off = 32; off > 0; off >>= 1) {
#pragma unroll
    for (int e = 0; e < NE; ++e) acc[e] += __shfl_down(acc[e], off);
  }
  __shared__ float red[4][NE];
  const int wid = tid >> 6, lane = tid & 63;
  if (lane == 0) {
#pragma unroll
    for (int e = 0; e < NE; ++e) red[wid][e] = acc[e];
  }
  __syncthreads();
  if (tid == 0) {
    float lg[NE];
#pragma unroll
    for (int e = 0; e < NE; ++e) lg[e] = red[0][e] + red[1][e] + red[2][e] + red[3][e];
    float m = lg[0];
    for (int e = 1; e < NE; ++e) m = fmaxf(m, lg[e]);
    float ex[NE], s = 0.f;
    for (int e = 0; e < NE; ++e) { ex[e] = expf(lg[e] - m); s += ex[e]; }
    const float inv = 1.f / s;
    int best = 0; float bb = ex[0] * inv + gate_b[0];
    for (int e = 1; e < NE; ++e) {
      const float b = ex[e] * inv + gate_b[e];
      if (b > bb) { bb = b; best = e; }
    }
    eidx[t] = best;
    ewgt[t] = ex[best] * inv;
  }
}

// ---------------- routing: count + prefix + scatter + two worklists (both BM=128) ----------------
__global__ __launch_bounds__(256) void route_kernel(
    const int* __restrict__ eidx, int* __restrict__ perm,
    int* __restrict__ pos_of, int4* __restrict__ wl1, int* __restrict__ n1,
    int4* __restrict__ wl2, int* __restrict__ n2)
{
  __shared__ int cnt[NE], off[NE], bas[NE + 1];
  const int tid = threadIdx.x;
  if (tid < NE) cnt[tid] = 0;
  __syncthreads();
  for (int t = tid; t < TOK; t += 256) atomicAdd(&cnt[eidx[t]], 1);
  __syncthreads();
  if (tid == 0) {
    int run = 0;
    for (int e = 0; e < NE; ++e) { bas[e] = run; off[e] = run; run += cnt[e]; }
    bas[NE] = run;
    int n = 0;
    for (int e = 0; e < NE; ++e)
      for (int r0 = 0; r0 < cnt[e]; r0 += 128) {
        int rows = cnt[e] - r0; if (rows > 128) rows = 128;
        wl1[n++] = make_int4(bas[e] + r0, rows, e, 0);
      }
    for (int r0 = 0; r0 < TOK; r0 += 128) wl1[n++] = make_int4(r0, 128, NE, 0);
    *n1 = n;
    n = 0;
    for (int e = 0; e < NE; ++e)
      for (int r0 = 0; r0 < cnt[e]; r0 += 128) {
        int rows = cnt[e] - r0; if (rows > 128) rows = 128;
        wl2[n++] = make_int4(bas[e] + r0, rows, e, 0);
      }
    for (int r0 = 0; r0 < TOK; r0 += 128) wl2[n++] = make_int4(r0, 128, NE, 0);
    *n2 = n;
  }
  __syncthreads();
  for (int t = tid; t < TOK; t += 256) {
    const int e = eidx[t];
    const int p = atomicAdd(&off[e], 1);
    perm[p] = t;
    pos_of[t] = p;
  }
}

// ---------------- mlp1: BM=128 x BN=256 x BK=64, 8 waves, dbuf + vmcnt(6) ----------------
// bid = nt*S1MAX + slot with S1MAX%8==0  ->  xcd = bid%8 = slot%8: all 8 nt-blocks of a
// slot share one XCD, so the slot's A-tile (256KB) becomes L2-resident (A was 50% of the
// L3-bound staging traffic). BN=256 halves the number of A re-stages vs BN=128.
// Staging swizzle (source XOR pre-swizzle + koff XOR read) is the round-0 proven
// 0-conflict pattern, unchanged.
__global__ __launch_bounds__(512) void mlp1_kernel(
    const bf16* __restrict__ x_bf, const bf16* __restrict__ w13,
    const bf16* __restrict__ ws13,
    const int* __restrict__ perm, const int4* __restrict__ wl,
    const int* __restrict__ wl_n,
    bf16* __restrict__ h_r, bf16* __restrict__ h_s,
    float* __restrict__ ss_r, float* __restrict__ ss_z)
{
  const int bid = blockIdx.x;
  const int slot = bid % S1MAX, nt = bid / S1MAX;   // nt in 0..7
  if (slot >= *wl_n) return;
  const int4 wle = wl[slot];
  const int mbase = wle.x, rows = wle.y, eid = wle.z;
  const int tid = threadIdx.x;
  const bool routed = (eid < NE);
  const bf16* bmat = routed ? w13 + (size_t)eid * 2046 * 1024 : ws13;
  bf16* hbuf  = routed ? h_r : h_s;
  float* ssbuf = routed ? ss_r : ss_z;

  extern __shared__ __align__(16) bf16 smem[];
  bf16* const Asb[2] = {smem, smem + 8192};             // 128x64 each
  bf16* const Bsb[2] = {smem + 16384, smem + 32768};    // 256x64 each
  __shared__ int toks[128];
  if (tid < 128) {
    int r = tid < rows ? tid : rows - 1;
    toks[tid] = routed ? perm[mbase + r] : (mbase + r);
  }
  __syncthreads();

  const int wid = tid >> 6, lane = tid & 63;
  const int srow = lane >> 3;
  const int kbg  = (lane & 7) ^ (srow & 7);
  // per wave per stage: 2 A-instrs (16 rows) + 4 B-instrs (32 rows), 16B/lane
  const bf16 *aG0, *aG1, *bG0, *bG1, *bG2, *bG3;
  int aL0o, aL1o, bL0o, bL1o, bL2o, bL3o;
  {
    const int r0a = wid * 16;
    aG0 = x_bf + (size_t)toks[r0a + 0 + srow] * 1024 + kbg * 8;
    aG1 = x_bf + (size_t)toks[r0a + 8 + srow] * 1024 + kbg * 8;
    aL0o = (r0a + 0) * 64; aL1o = (r0a + 8) * 64;
    const int r0b = wid * 32;
    int b0 = nt * 256 + r0b +  0 + srow; if (b0 > 2045) b0 = 2045;
    int b1 = nt * 256 + r0b +  8 + srow; if (b1 > 2045) b1 = 2045;
    int b2 = nt * 256 + r0b + 16 + srow; if (b2 > 2045) b2 = 2045;
    int b3 = nt * 256 + r0b + 24 + srow; if (b3 > 2045) b3 = 2045;
    bG0 = bmat + (size_t)b0 * 1024 + kbg * 8;
    bG1 = bmat + (size_t)b1 * 1024 + kbg * 8;
    bG2 = bmat + (size_t)b2 * 1024 + kbg * 8;
    bG3 = bmat + (size_t)b3 * 1024 + kbg * 8;
    bL0o = (r0b +  0) * 64; bL1o = (r0b +  8) * 64;
    bL2o = (r0b + 16) * 64; bL3o = (r0b + 24) * 64;
  }

  const int lrow = lane & 15, quad = lane >> 4, sw = lane & 7;
  const int wrow = (wid >> 2) * 64, wcol = (wid & 3) * 64;
  int aoff[4], boff[4], koff[2];
#pragma unroll
  for (int mi = 0; mi < 4; ++mi) aoff[mi] = (wrow + mi * 16 + lrow) * 64;
#pragma unroll
  for (int ni = 0; ni < 4; ++ni) boff[ni] = (wcol + ni * 16 + lrow) * 64;
#pragma unroll
  for (int kk = 0; kk < 2; ++kk) koff[kk] = ((kk * 4 + quad) ^ sw) * 8;

  const floatx4 fz = {0.f, 0.f, 0.f, 0.f};
  floatx4 acc[4][4];
#pragma unroll
  for (int mi = 0; mi < 4; ++mi)
#pragma unroll
    for (int ni = 0; ni < 4; ++ni) acc[mi][ni] = fz;

#define STAGE1(KE, BUF) { \
    load_lds16(aG0 + (KE), Asb[BUF] + aL0o); load_lds16(aG1 + (KE), Asb[BUF] + aL1o); \
    load_lds16(bG0 + (KE), Bsb[BUF] + bL0o); load_lds16(bG1 + (KE), Bsb[BUF] + bL1o); \
    load_lds16(bG2 + (KE), Bsb[BUF] + bL2o); load_lds16(bG3 + (KE), Bsb[BUF] + bL3o); }

#define COMP1(BUF) { \
_Pragma("unroll") \
    for (int kk = 0; kk < 2; ++kk) { \
      bf16x8 av[4], bv[4]; \
_Pragma("unroll") \
      for (int mi = 0; mi < 4; ++mi) av[mi] = *(const bf16x8*)(Asb[BUF] + aoff[mi] + koff[kk]); \
_Pragma("unroll") \
      for (int ni = 0; ni < 4; ++ni) bv[ni] = *(const bf16x8*)(Bsb[BUF] + boff[ni] + koff[kk]); \
_Pragma("unroll") \
      for (int mi = 0; mi < 4; ++mi) \
_Pragma("unroll") \
        for (int ni = 0; ni < 4; ++ni) \
          acc[mi][ni] = MFMA16(av[mi], bv[ni], acc[mi][ni]); \
    } }

  STAGE1(0, 0)
  STAGE1(64, 1)
#pragma unroll 1
  for (int t = 0; t < 7; ++t) {
    const int ke = t * 128;
    WBAR(6); COMP1(0) BARO; STAGE1(ke + 128, 0)
    WBAR(6); COMP1(1) BARO; STAGE1(ke + 192, 1)
  }
  WBAR(6); COMP1(0)
  WBAR(0); COMP1(1)
#undef STAGE1
#undef COMP1

  // epilogue: interleaved cols -> (s1,s3) via lane^1 shuffle, gate, store h(bf16), sumsq
#pragma unroll
  for (int mi = 0; mi < 4; ++mi) {
#pragma unroll
    for (int r = 0; r < 4; ++r) {
      const int row = wrow + mi * 16 + quad * 4 + r;
      const bool rowok = row < rows;
      float ssum = 0.f;
#pragma unroll
      for (int ni = 0; ni < 4; ++ni) {
        const float c = acc[mi][ni][r];
        const float partner = __shfl_xor(c, 1);
        const float s1 = (lane & 1) ? partner : c;
        const float s3 = (lane & 1) ? c : partner;
        const float sp = (s1 / (1.f + __expf(-s1))) * s3;
        const int P = (nt * 256 + wcol + ni * 16 + lrow) >> 1;
        const bool ok = rowok && ((lane & 1) == 0) && (P < 1023);
        if (ok) hbuf[(size_t)(mbase + row) * 1024 + 1 + P] = (bf16)sp;
        ssum += ok ? sp * sp : 0.f;
      }
      ssum += __shfl_xor(ssum, 1);
      ssum += __shfl_xor(ssum, 2);
      ssum += __shfl_xor(ssum, 4);
      ssum += __shfl_xor(ssum, 8);
      if (lrow == 0 && rowok) atomicAdd(ssbuf + mbase + row, ssum);
    }
  }
}

// ---------------- h[:,0] = sqrt(sumsq + 1) ----------------
__global__ __launch_bounds__(256) void finalize_t_kernel(
    const float* __restrict__ ss_r, const float* __restrict__ ss_z,
    bf16* __restrict__ h_r, bf16* __restrict__ h_s)
{
  const int i = blockIdx.x * 256 + threadIdx.x;
  if (i < TOK) {
    h_r[(size_t)i * 1024] = (bf16)sqrtf(ss_r[i] + 1.0f);
    h_s[(size_t)i * 1024] = (bf16)sqrtf(ss_z[i] + 1.0f);
  }
}

// ---------------- mlp2: BM=128 x BN=128 x BK=64, 4 waves, dbuf + vmcnt(8) ----------------
// Clone of the round-0 proven mlp1 structure. BM=64 -> 128 halves slot count and thus
// B-staging traffic. Same xcd = slot%8 locality trick (S2MAX%8==0).
__global__ __launch_bounds__(256) void mlp2_kernel(
    const bf16* __restrict__ h_r, const bf16* __restrict__ h_s,
    const bf16* __restrict__ w2b, const bf16* __restrict__ ws2b,
    const int4* __restrict__ wl, const int* __restrict__ wl_n,
    float* __restrict__ o_r, float* __restrict__ o_s,
    float* __restrict__ ss_or, float* __restrict__ ss_oz)
{
  const int bid = blockIdx.x;
  const int slot = bid % S2MAX, nt = bid / S2MAX;   // nt in 0..7
  if (slot >= *wl_n) return;
  const int4 wle = wl[slot];
  const int mbase = wle.x, rows = wle.y, eid = wle.z;
  const int tid = threadIdx.x;
  const bool routed = (eid < NE);
  const bf16* abuf = routed ? h_r : h_s;
  const bf16* bmat = routed ? w2b + (size_t)eid * 1023 * 1024 : ws2b;
  float* obuf  = routed ? o_r : o_s;
  float* ssbuf = routed ? ss_or : ss_oz;
  const int n0 = nt * 128;

  __shared__ __align__(16) bf16 As[2][128 * 64];
  __shared__ __align__(16) bf16 Bs[2][128 * 64];

  const int wid = tid >> 6, lane = tid & 63;
  const int srow = lane >> 3;
  const int kbg  = (lane & 7) ^ (srow & 7);
  const bf16 *aG0, *aG1, *aG2, *aG3, *bG0, *bG1, *bG2, *bG3;
  int aL0o, aL1o, aL2o, aL3o, bL0o, bL1o, bL2o, bL3o;
  {
    const int r0 = wid * 32;
    int ra0 = r0 +  0 + srow; if (ra0 >= rows) ra0 = rows - 1;
    int ra1 = r0 +  8 + srow; if (ra1 >= rows) ra1 = rows - 1;
    int ra2 = r0 + 16 + srow; if (ra2 >= rows) ra2 = rows - 1;
    int ra3 = r0 + 24 + srow; if (ra3 >= rows) ra3 = rows - 1;
    aG0 = abuf + (size_t)(mbase + ra0) * 1024 + kbg * 8;
    aG1 = abuf + (size_t)(mbase + ra1) * 1024 + kbg * 8;
    aG2 = abuf + (size_t)(mbase + ra2) * 1024 + kbg * 8;
    aG3 = abuf + (size_t)(mbase + ra3) * 1024 + kbg * 8;
    aL0o = (r0 +  0) * 64; aL1o = (r0 +  8) * 64;
    aL2o = (r0 + 16) * 64; aL3o = (r0 + 24) * 64;
    int b0 = n0 + r0 +  0 + srow; if (b0 > 1022) b0 = 1022;
    int b1 = n0 + r0 +  8 + srow; if (b1 > 1022) b1 = 1022;
    int b2 = n0 + r0 + 16 + srow; if (b2 > 1022) b2 = 1022;
    int b3 = n0 + r0 + 24 + srow; if (b3 > 1022) b3 = 1022;
    bG0 = bmat + (size_t)b0 * 1024 + kbg * 8;
    bG1 = bmat + (size_t)b1 * 1024 + kbg * 8;
    bG2 = bmat + (size_t)b2 * 1024 + kbg * 8;
    bG3 = bmat + (size_t)b3 * 1024 + kbg * 8;
    bL0o = (r0 +  0) * 64; bL1o = (r0 +  8) * 64;
    bL2o = (r0 + 16) * 64; bL3o = (r0 + 24) * 64;
  }

  const int lrow = lane & 15, quad = lane >> 4, sw = lane & 7;
  const int wrow = (wid >> 1) * 64, wcol = (wid & 1) * 64;
  int aoff[4], boff[4], koff[2];
#pragma unroll
  for (int mi = 0; mi < 4; ++mi) aoff[mi] = (wrow + mi * 16 + lrow) * 64;
#pragma unroll
  for (int ni = 0; ni < 4; ++ni) boff[ni] = (wcol + ni * 16 + lrow) * 64;
#pragma unroll
  for (int kk = 0; kk < 2; ++kk) koff[kk] = ((kk * 4 + quad) ^ sw) * 8;

  const floatx4 fz = {0.f, 0.f, 0.f, 0.f};
  floatx4 acc[4][4];
#pragma unroll
  for (int mi = 0; mi < 4; ++mi)
#pragma unroll
    for (int ni = 0; ni < 4; ++ni) acc[mi][ni] = fz;

#define STAGE2(KE, BUF) { \
    load_lds16(aG0 + (KE), As[BUF] + aL0o); load_lds16(aG1 + (KE), As[BUF] + aL1o); \
    load_lds16(aG2 + (KE), As[BUF] + aL2o); load_lds16(aG3 + (KE), As[BUF] + aL3o); \
    load_lds16(bG0 + (KE), Bs[BUF] + bL0o); load_lds16(bG1 + (KE), Bs[BUF] + bL1o); \
    load_lds16(bG2 + (KE), Bs[BUF] + bL2o); load_lds16(bG3 + (KE), Bs[BUF] + bL3o); }

#define COMP2(BUF) { \
_Pragma("unroll") \
    for (int kk = 0; kk < 2; ++kk) { \
      bf16x8 av[4], bv[4]; \
_Pragma("unroll") \
      for (int mi = 0; mi < 4; ++mi) av[mi] = *(const bf16x8*)(As[BUF] + aoff[mi] + koff[kk]); \
_Pragma("unroll") \
      for (int ni = 0; ni < 4; ++ni) bv[ni] = *(const bf16x8*)(Bs[BUF] + boff[ni] + koff[kk]); \
_Pragma("unroll") \
      for (int mi = 0; mi < 4; ++mi) \
_Pragma("unroll") \
        for (int ni = 0; ni < 4; ++ni) \
          acc[mi][ni] = MFMA16(av[mi], bv[ni], acc[mi][ni]); \
    } }

  STAGE2(0, 0)
  STAGE2(64, 1)
#pragma unroll 1
  for (int t = 0; t < 7; ++t) {
    const int ke = t * 128;
    WBAR(8); COMP2(0) BARO; STAGE2(ke + 128, 0)
    WBAR(8); COMP2(1) BARO; STAGE2(ke + 192, 1)
  }
  WBAR(8); COMP2(0)
  WBAR(0); COMP2(1)
#undef STAGE2
#undef COMP2

#pragma unroll
  for (int mi = 0; mi < 4; ++mi) {
#pragma unroll
    for (int r = 0; r < 4; ++r) {
      const int row = wrow + mi * 16 + quad * 4 + r;
      const bool rowok = row < rows;
      float ssum = 0.f;
#pragma unroll
      for (int ni = 0; ni < 4; ++ni) {
        const float v = acc[mi][ni][r];
        const int n = n0 + wcol + ni * 16 + lrow;
        const bool ok = rowok && (n < 1023);
        if (ok) obuf[(size_t)(mbase + row) * 1024 + n] = v;
        ssum += ok ? v * v : 0.f;
      }
      ssum += __shfl_xor(ssum, 1);
      ssum += __shfl_xor(ssum, 2);
      ssum += __shfl_xor(ssum, 4);
      ssum += __shfl_xor(ssum, 8);
      if (lrow == 0 && rowok) atomicAdd(ssbuf + mbase + row, ssum);
    }
  }
}

// ---------------- final LResNet combine + Lorentz normalize ----------------
__global__ __launch_bounds__(256) void combine_kernel(
    const float* __restrict__ o_r, const float* __restrict__ o_s,
    const float* __restrict__ ss_or, const float* __restrict__ ss_oz,
    const int* __restrict__ pos_of, const float* __restrict__ wgt,
    float* __restrict__ out)
{
  const int t = blockIdx.x, tid = threadIdx.x;
  const int p = pos_of[t];
  const float w = wgt[t];
  const float4 oz = ((const float4*)(o_s + (size_t)t * 1024))[tid];
  const float4 oe = ((const float4*)(o_r + (size_t)p * 1024))[tid];
  const float tw = 2.f * w;
  float c0 = oz.x + tw * oe.x;
  float c1 = oz.y + tw * oe.y;
  float c2 = oz.z + tw * oe.z;
  float c3 = (tid == 255) ? 0.f : (oz.w + tw * oe.w);  // n=1023 is padding
  float ssum = c0 * c0 + c1 * c1 + c2 * c2 + c3 * c3;
#pragma unroll
  for (int off = 32; off > 0; off >>= 1) ssum += __shfl_down(ssum, off);
  __shared__ float rs[4];
  if ((tid & 63) == 0) rs[tid >> 6] = ssum;
  __syncthreads();
  const float space2 = rs[0] + rs[1] + rs[2] + rs[3];
  const float comb0 = sqrtf(ss_oz[t] + 1.f) + 2.f + 2.f * w * sqrtf(ss_or[p] + 1.f);
  const float li = space2 - comb0 * comb0;
  const float inv = 1.f / sqrtf(fmaxf(fabsf(li), 1e-8f));
  float* orow = out + (size_t)t * 1024;
  const int j = 1 + tid * 4;
  orow[j]     = c0 * inv;
  orow[j + 1] = c1 * inv;
  orow[j + 2] = c2 * inv;
  if (tid != 255) orow[j + 3] = c3 * inv;
  if (tid == 0) orow[0] = comb0 * inv;
}

extern "C" void kernel_launch(void* const* d_in, const int* in_sizes, int n_in,
                              void* d_out, int out_size, void* d_ws, size_t ws_size,
                              hipStream_t stream) {
  const float* x      = (const float*)d_in[0];
  const float* gate_w = (const float*)d_in[1];
  const float* gate_b = (const float*)d_in[2];
  const float* W1     = (const float*)d_in[3];
  const float* W3     = (const float*)d_in[4];
  const float* W2     = (const float*)d_in[5];
  const float* Ws1    = (const float*)d_in[6];
  const float* Ws3    = (const float*)d_in[7];
  const float* Ws2    = (const float*)d_in[8];
  float* out = (float*)d_out;

  char* ws = (char*)d_ws;
  size_t off = 0;
  auto alloc = [&](size_t bytes) {
    void* p = ws + off;
    off += (bytes + 255) & ~(size_t)255;
    return p;
  };
  bf16*  x_bf = (bf16*) alloc((size_t)TOK * 1024 * 2);
  bf16*  h_r  = (bf16*) alloc((size_t)TOK * 1024 * 2);
  bf16*  h_s  = (bf16*) alloc((size_t)TOK * 1024 * 2);
  float* o_r  = (float*)alloc((size_t)TOK * 1024 * 4);
  float* o_s  = (float*)alloc((size_t)TOK * 1024 * 4);
  float* ss   = (float*)alloc((size_t)4 * TOK * 4);
  int*   eidx = (int*)  alloc((size_t)TOK * 4);
  float* ewgt = (float*)alloc((size_t)TOK * 4);
  int*   perm = (int*)  alloc((size_t)TOK * 4);
  int*   posf = (int*)  alloc((size_t)TOK * 4);
  int4*  wl1  = (int4*) alloc((size_t)S1MAX * 16);
  int4*  wl2  = (int4*) alloc((size_t)S2MAX * 16);
  int*   wn   = (int*)  alloc(32);
  bf16*  w13  = (bf16*) alloc((size_t)8 * 2046 * 1024 * 2);
  bf16*  ws13 = (bf16*) alloc((size_t)2046 * 1024 * 2);
  bf16*  w2b  = (bf16*) alloc((size_t)8 * 1023 * 1024 * 2);
  bf16*  ws2b = (bf16*) alloc((size_t)1023 * 1024 * 2);

  float* ss_r  = ss;
  float* ss_z  = ss + TOK;
  float* ss_or = ss + 2 * TOK;
  float* ss_oz = ss + 3 * TOK;

  // mlp1 uses 96KB dynamic LDS (2-buffer, 128x64 A + 256x64 B) — opt in above 64KB.
  const int MLP1_LDS = 2 * (128 * 64 + 256 * 64) * 2;  // 98304 B
  (void)hipFuncSetAttribute((const void*)mlp1_kernel,
                            hipFuncAttributeMaxDynamicSharedMemorySize, MLP1_LDS);

  convert_kernel<<<NCVT, 128, 0, stream>>>(W1, W3, W2, Ws1, Ws3, Ws2,
                                           w13, ws13, w2b, ws2b);
  gate_cvt_kernel<<<TOK, 256, 0, stream>>>(x, gate_w, gate_b, x_bf, eidx, ewgt, ss);
  route_kernel<<<1, 256, 0, stream>>>(eidx, perm, posf, wl1, wn, wl2, wn + 1);
  mlp1_kernel<<<8 * S1MAX, 512, MLP1_LDS, stream>>>(x_bf, w13, ws13, perm, wl1, wn,
                                                    h_r, h_s, ss_r, ss_z);
  finalize_t_kernel<<<8, 256, 0, stream>>>(ss_r, ss_z, h_r, h_s);
  mlp2_kernel<<<8 * S2MAX, 256, 0, stream>>>(h_r, h_s, w2b, ws2b, wl2, wn + 1,
                                             o_r, o_s, ss_or, ss_oz);
  combine_kernel<<<TOK, 256, 0, stream>>>(o_r, o_s, ss_or, ss_oz, posf, ewgt, out);
}

// Round 4
// 246.111 us; speedup vs baseline: 1.0257x; 1.0257x over previous
//
#include <hip/hip_runtime.h>

typedef __bf16 bf16;
typedef __attribute__((ext_vector_type(8))) __bf16 bf16x8;
typedef __attribute__((ext_vector_type(4))) float floatx4;

#define TOK 2048
#define DD  1024
#define NE  8
#define SMAX 24   // worklist slots (BM=256): <=15 routed + 8 shared, padded to %8==0

#define MFMA16(A,B,C) __builtin_amdgcn_mfma_f32_16x16x32_bf16(A,B,C,0,0,0)

__device__ __forceinline__ void load_lds16(const bf16* g, bf16* l) {
  __builtin_amdgcn_global_load_lds(
      (const __attribute__((address_space(1))) void*)g,
      (__attribute__((address_space(3))) void*)l, 16, 0, 0);
}

// fine-grained barrier: wait only the OLDEST outstanding loads, keep N in flight
#define WBAR(N) asm volatile("s_waitcnt vmcnt(" #N ")\n\ts_barrier" ::: "memory")
#define BARO    asm volatile("s_barrier" ::: "memory")

__device__ __forceinline__ uint4 pack_bf8(float4 a, float4 b) {
  union { bf16 h[8]; uint4 u; } p;
  p.h[0] = (bf16)a.x; p.h[1] = (bf16)a.y; p.h[2] = (bf16)a.z; p.h[3] = (bf16)a.w;
  p.h[4] = (bf16)b.x; p.h[5] = (bf16)b.y; p.h[6] = (bf16)b.z; p.h[7] = (bf16)b.w;
  return p.u;
}

// ---------------- weight fp32 -> bf16 conversion (W1/W3 row-interleaved) ----------------
#define NCVT (8*2046 + 2046 + 8*1023 + 1023)
__global__ __launch_bounds__(128) void convert_kernel(
    const float* __restrict__ W1, const float* __restrict__ W3,
    const float* __restrict__ W2, const float* __restrict__ Ws1,
    const float* __restrict__ Ws3, const float* __restrict__ Ws2,
    bf16* __restrict__ w13, bf16* __restrict__ ws13,
    bf16* __restrict__ w2b, bf16* __restrict__ ws2b)
{
  const int r = blockIdx.x, tid = threadIdx.x;
  const float* src; bf16* dst;
  if (r < 8 * 2046) {
    const int e = r / 2046, q = r % 2046;
    src = ((q & 1) ? W3 : W1) + ((size_t)e * 1023 + (q >> 1)) * 1024;
    dst = w13 + (size_t)r * 1024;
  } else if (r < 8 * 2046 + 2046) {
    const int q = r - 8 * 2046;
    src = ((q & 1) ? Ws3 : Ws1) + (size_t)(q >> 1) * 1024;
    dst = ws13 + (size_t)q * 1024;
  } else if (r < 8 * 2046 + 2046 + 8 * 1023) {
    const int q = r - (8 * 2046 + 2046);
    src = W2 + (size_t)q * 1024;
    dst = w2b + (size_t)q * 1024;
  } else {
    const int q = r - (8 * 2046 + 2046 + 8 * 1023);
    src = Ws2 + (size_t)q * 1024;
    dst = ws2b + (size_t)q * 1024;
  }
  const float4 f0 = ((const float4*)src)[tid * 2];
  const float4 f1 = ((const float4*)src)[tid * 2 + 1];
  ((uint4*)dst)[tid] = pack_bf8(f0, f1);
}

// ---------------- gate + x->bf16 + ss zero-init ----------------
__global__ __launch_bounds__(256) void gate_cvt_kernel(
    const float* __restrict__ x, const float* __restrict__ gate_w,
    const float* __restrict__ gate_b, bf16* __restrict__ x_bf,
    int* __restrict__ eidx, float* __restrict__ ewgt, float* __restrict__ ss)
{
  const int t = blockIdx.x, tid = threadIdx.x;
  if (tid < 4) ss[tid * TOK + t] = 0.f;
  const float4 v = ((const float4*)(x + (size_t)t * DD))[tid];
  union { bf16 h[4]; uint2 u; } pk;
  pk.h[0] = (bf16)v.x; pk.h[1] = (bf16)v.y; pk.h[2] = (bf16)v.z; pk.h[3] = (bf16)v.w;
  ((uint2*)(x_bf + (size_t)t * DD))[tid] = pk.u;

  float acc[NE];
#pragma unroll
  for (int e = 0; e < NE; ++e) acc[e] = 0.f;
  const float vv[4] = {v.x, v.y, v.z, v.w};
#pragma unroll
  for (int i = 0; i < 4; ++i) {
    const int d = tid * 4 + i;
    if (d >= 1) {
#pragma unroll
      for (int e = 0; e < NE; ++e) acc[e] += vv[i] * gate_w[e * (DD - 1) + d - 1];
    }
  }
#pragma unroll
  for (int off = 32; off > 0; off >>= 1) {
#pragma unroll
    for (int e = 0; e < NE; ++e) acc[e] += __shfl_down(acc[e], off);
  }
  __shared__ float red[4][NE];
  const int wid = tid >> 6, lane = tid & 63;
  if (lane == 0) {
#pragma unroll
    for (int e = 0; e < NE; ++e) red[wid][e] = acc[e];
  }
  __syncthreads();
  if (tid == 0) {
    float lg[NE];
#pragma unroll
    for (int e = 0; e < NE; ++e) lg[e] = red[0][e] + red[1][e] + red[2][e] + red[3][e];
    float m = lg[0];
    for (int e = 1; e < NE; ++e) m = fmaxf(m, lg[e]);
    float ex[NE], s = 0.f;
    for (int e = 0; e < NE; ++e) { ex[e] = expf(lg[e] - m); s += ex[e]; }
    const float inv = 1.f / s;
    int best = 0; float bb = ex[0] * inv + gate_b[0];
    for (int e = 1; e < NE; ++e) {
      const float b = ex[e] * inv + gate_b[e];
      if (b > bb) { bb = b; best = e; }
    }
    eidx[t] = best;
    ewgt[t] = ex[best] * inv;
  }
}

// ---------------- routing: count + prefix + scatter + single BM=256 worklist ----------------
__global__ __launch_bounds__(256) void route_kernel(
    const int* __restrict__ eidx, int* __restrict__ perm,
    int* __restrict__ pos_of, int4* __restrict__ wl, int* __restrict__ n1)
{
  __shared__ int cnt[NE], off[NE], bas[NE + 1];
  const int tid = threadIdx.x;
  if (tid < NE) cnt[tid] = 0;
  __syncthreads();
  for (int t = tid; t < TOK; t += 256) atomicAdd(&cnt[eidx[t]], 1);
  __syncthreads();
  if (tid == 0) {
    int run = 0;
    for (int e = 0; e < NE; ++e) { bas[e] = run; off[e] = run; run += cnt[e]; }
    bas[NE] = run;
    int n = 0;
    for (int e = 0; e < NE; ++e)
      for (int r0 = 0; r0 < cnt[e]; r0 += 256) {
        int rows = cnt[e] - r0; if (rows > 256) rows = 256;
        wl[n++] = make_int4(bas[e] + r0, rows, e, 0);
      }
    for (int r0 = 0; r0 < TOK; r0 += 256) wl[n++] = make_int4(r0, 256, NE, 0);
    *n1 = n;
  }
  __syncthreads();
  for (int t = tid; t < TOK; t += 256) {
    const int e = eidx[t];
    const int p = atomicAdd(&off[e], 1);
    perm[p] = t;
    pos_of[t] = p;
  }
}

// ---------------- mlp1: BM=256 x BN=256 x BK=64, 16 waves, dbuf + vmcnt(4) ----------------
// Staged bytes per output tile scale as (BM+BN)*K: 256x256 stages 0.75x the bytes of
// 128x256 per output element -> total staged ~144MB vs ~203MB (the measured limiter is
// L3/fabric-served staging traffic; latency-schedule variants r0-r3 all pinned at 54us).
// LDS = 2*(256*64+256*64)*2B = 128KB dbuf. Per-wave 4 stage instrs -> WBAR(4).
// bid = nt*SMAX + slot, SMAX%8==0 -> xcd = slot%8: a slot's nt-blocks share one XCD
// (A-tile 512KB becomes L2-resident). Swizzle = r0-proven 0-conflict pattern.
__global__ __launch_bounds__(1024) void mlp1_kernel(
    const bf16* __restrict__ x_bf, const bf16* __restrict__ w13,
    const bf16* __restrict__ ws13,
    const int* __restrict__ perm, const int4* __restrict__ wl,
    const int* __restrict__ wl_n,
    bf16* __restrict__ h_r, bf16* __restrict__ h_s,
    float* __restrict__ ss_r, float* __restrict__ ss_z)
{
  const int bid = blockIdx.x;
  const int slot = bid % SMAX, nt = bid / SMAX;   // nt in 0..7
  if (slot >= *wl_n) return;
  const int4 wle = wl[slot];
  const int mbase = wle.x, rows = wle.y, eid = wle.z;
  const int tid = threadIdx.x;
  const bool routed = (eid < NE);
  const bf16* bmat = routed ? w13 + (size_t)eid * 2046 * 1024 : ws13;
  bf16* hbuf  = routed ? h_r : h_s;
  float* ssbuf = routed ? ss_r : ss_z;

  extern __shared__ __align__(16) bf16 smem[];
  bf16* const Asb[2] = {smem, smem + 16384};            // 256x64 each
  bf16* const Bsb[2] = {smem + 32768, smem + 49152};    // 256x64 each
  __shared__ int toks[256];
  if (tid < 256) {
    int r = tid < rows ? tid : rows - 1;
    toks[tid] = routed ? perm[mbase + r] : (mbase + r);
  }
  __syncthreads();

  const int wid = tid >> 6, lane = tid & 63;
  const int srow = lane >> 3;
  const int kbg  = (lane & 7) ^ (srow & 7);
  // per wave per stage: 2 A-instrs (16 rows) + 2 B-instrs (16 rows), 16B/lane
  const bf16 *aG0, *aG1, *bG0, *bG1;
  int aL0o, aL1o, bL0o, bL1o;
  {
    const int r0 = wid * 16;
    aG0 = x_bf + (size_t)toks[r0 + 0 + srow] * 1024 + kbg * 8;
    aG1 = x_bf + (size_t)toks[r0 + 8 + srow] * 1024 + kbg * 8;
    aL0o = (r0 + 0) * 64; aL1o = (r0 + 8) * 64;
    int b0 = nt * 256 + r0 + 0 + srow; if (b0 > 2045) b0 = 2045;
    int b1 = nt * 256 + r0 + 8 + srow; if (b1 > 2045) b1 = 2045;
    bG0 = bmat + (size_t)b0 * 1024 + kbg * 8;
    bG1 = bmat + (size_t)b1 * 1024 + kbg * 8;
    bL0o = (r0 + 0) * 64; bL1o = (r0 + 8) * 64;
  }

  const int lrow = lane & 15, quad = lane >> 4, sw = lane & 7;
  const int wrow = (wid >> 2) * 64, wcol = (wid & 3) * 64;
  int aoff[4], boff[4], koff[2];
#pragma unroll
  for (int mi = 0; mi < 4; ++mi) aoff[mi] = (wrow + mi * 16 + lrow) * 64;
#pragma unroll
  for (int ni = 0; ni < 4; ++ni) boff[ni] = (wcol + ni * 16 + lrow) * 64;
#pragma unroll
  for (int kk = 0; kk < 2; ++kk) koff[kk] = ((kk * 4 + quad) ^ sw) * 8;

  const floatx4 fz = {0.f, 0.f, 0.f, 0.f};
  floatx4 acc[4][4];
#pragma unroll
  for (int mi = 0; mi < 4; ++mi)
#pragma unroll
    for (int ni = 0; ni < 4; ++ni) acc[mi][ni] = fz;

#define STAGE1(KE, BUF) { \
    load_lds16(aG0 + (KE), Asb[BUF] + aL0o); load_lds16(aG1 + (KE), Asb[BUF] + aL1o); \
    load_lds16(bG0 + (KE), Bsb[BUF] + bL0o); load_lds16(bG1 + (KE), Bsb[BUF] + bL1o); }

#define COMP1(BUF) { \
_Pragma("unroll") \
    for (int kk = 0; kk < 2; ++kk) { \
      bf16x8 av[4], bv[4]; \
_Pragma("unroll") \
      for (int mi = 0; mi < 4; ++mi) av[mi] = *(const bf16x8*)(Asb[BUF] + aoff[mi] + koff[kk]); \
_Pragma("unroll") \
      for (int ni = 0; ni < 4; ++ni) bv[ni] = *(const bf16x8*)(Bsb[BUF] + boff[ni] + koff[kk]); \
_Pragma("unroll") \
      for (int mi = 0; mi < 4; ++mi) \
_Pragma("unroll") \
        for (int ni = 0; ni < 4; ++ni) \
          acc[mi][ni] = MFMA16(av[mi], bv[ni], acc[mi][ni]); \
    } }

  STAGE1(0, 0)
  STAGE1(64, 1)
#pragma unroll 1
  for (int t = 0; t < 7; ++t) {
    const int ke = t * 128;
    WBAR(4); COMP1(0) BARO; STAGE1(ke + 128, 0)
    WBAR(4); COMP1(1) BARO; STAGE1(ke + 192, 1)
  }
  WBAR(4); COMP1(0)
  WBAR(0); COMP1(1)
#undef STAGE1
#undef COMP1

  // epilogue: interleaved cols -> (s1,s3) via lane^1 shuffle, gate, store h(bf16), sumsq
#pragma unroll
  for (int mi = 0; mi < 4; ++mi) {
#pragma unroll
    for (int r = 0; r < 4; ++r) {
      const int row = wrow + mi * 16 + quad * 4 + r;
      const bool rowok = row < rows;
      float ssum = 0.f;
#pragma unroll
      for (int ni = 0; ni < 4; ++ni) {
        const float c = acc[mi][ni][r];
        const float partner = __shfl_xor(c, 1);
        const float s1 = (lane & 1) ? partner : c;
        const float s3 = (lane & 1) ? c : partner;
        const float sp = (s1 / (1.f + __expf(-s1))) * s3;
        const int P = (nt * 256 + wcol + ni * 16 + lrow) >> 1;
        const bool ok = rowok && ((lane & 1) == 0) && (P < 1023);
        if (ok) hbuf[(size_t)(mbase + row) * 1024 + 1 + P] = (bf16)sp;
        ssum += ok ? sp * sp : 0.f;
      }
      ssum += __shfl_xor(ssum, 1);
      ssum += __shfl_xor(ssum, 2);
      ssum += __shfl_xor(ssum, 4);
      ssum += __shfl_xor(ssum, 8);
      if (lrow == 0 && rowok) atomicAdd(ssbuf + mbase + row, ssum);
    }
  }
}

// ---------------- h[:,0] = sqrt(sumsq + 1) ----------------
__global__ __launch_bounds__(256) void finalize_t_kernel(
    const float* __restrict__ ss_r, const float* __restrict__ ss_z,
    bf16* __restrict__ h_r, bf16* __restrict__ h_s)
{
  const int i = blockIdx.x * 256 + threadIdx.x;
  if (i < TOK) {
    h_r[(size_t)i * 1024] = (bf16)sqrtf(ss_r[i] + 1.0f);
    h_s[(size_t)i * 1024] = (bf16)sqrtf(ss_z[i] + 1.0f);
  }
}

// ---------------- mlp2: BM=256 x BN=256 x BK=64, 16 waves, dbuf + vmcnt(4) ----------------
// Same 256x256 traffic-minimal structure; nt in 0..3 (N=1023). Shares the BM=256 worklist.
__global__ __launch_bounds__(1024) void mlp2_kernel(
    const bf16* __restrict__ h_r, const bf16* __restrict__ h_s,
    const bf16* __restrict__ w2b, const bf16* __restrict__ ws2b,
    const int4* __restrict__ wl, const int* __restrict__ wl_n,
    float* __restrict__ o_r, float* __restrict__ o_s,
    float* __restrict__ ss_or, float* __restrict__ ss_oz)
{
  const int bid = blockIdx.x;
  const int slot = bid % SMAX, nt = bid / SMAX;   // nt in 0..3
  if (slot >= *wl_n) return;
  const int4 wle = wl[slot];
  const int mbase = wle.x, rows = wle.y, eid = wle.z;
  const int tid = threadIdx.x;
  const bool routed = (eid < NE);
  const bf16* abuf = routed ? h_r : h_s;
  const bf16* bmat = routed ? w2b + (size_t)eid * 1023 * 1024 : ws2b;
  float* obuf  = routed ? o_r : o_s;
  float* ssbuf = routed ? ss_or : ss_oz;
  const int n0 = nt * 256;

  extern __shared__ __align__(16) bf16 smem[];
  bf16* const Asb[2] = {smem, smem + 16384};            // 256x64 each
  bf16* const Bsb[2] = {smem + 32768, smem + 49152};    // 256x64 each

  const int wid = tid >> 6, lane = tid & 63;
  const int srow = lane >> 3;
  const int kbg  = (lane & 7) ^ (srow & 7);
  const bf16 *aG0, *aG1, *bG0, *bG1;
  int aL0o, aL1o, bL0o, bL1o;
  {
    const int r0 = wid * 16;
    int ra0 = r0 + 0 + srow; if (ra0 >= rows) ra0 = rows - 1;
    int ra1 = r0 + 8 + srow; if (ra1 >= rows) ra1 = rows - 1;
    aG0 = abuf + (size_t)(mbase + ra0) * 1024 + kbg * 8;
    aG1 = abuf + (size_t)(mbase + ra1) * 1024 + kbg * 8;
    aL0o = (r0 + 0) * 64; aL1o = (r0 + 8) * 64;
    int b0 = n0 + r0 + 0 + srow; if (b0 > 1022) b0 = 1022;
    int b1 = n0 + r0 + 8 + srow; if (b1 > 1022) b1 = 1022;
    bG0 = bmat + (size_t)b0 * 1024 + kbg * 8;
    bG1 = bmat + (size_t)b1 * 1024 + kbg * 8;
    bL0o = (r0 + 0) * 64; bL1o = (r0 + 8) * 64;
  }

  const int lrow = lane & 15, quad = lane >> 4, sw = lane & 7;
  const int wrow = (wid >> 2) * 64, wcol = (wid & 3) * 64;
  int aoff[4], boff[4], koff[2];
#pragma unroll
  for (int mi = 0; mi < 4; ++mi) aoff[mi] = (wrow + mi * 16 + lrow) * 64;
#pragma unroll
  for (int ni = 0; ni < 4; ++ni) boff[ni] = (wcol + ni * 16 + lrow) * 64;
#pragma unroll
  for (int kk = 0; kk < 2; ++kk) koff[kk] = ((kk * 4 + quad) ^ sw) * 8;

  const floatx4 fz = {0.f, 0.f, 0.f, 0.f};
  floatx4 acc[4][4];
#pragma unroll
  for (int mi = 0; mi < 4; ++mi)
#pragma unroll
    for (int ni = 0; ni < 4; ++ni) acc[mi][ni] = fz;

#define STAGE2(KE, BUF) { \
    load_lds16(aG0 + (KE), Asb[BUF] + aL0o); load_lds16(aG1 + (KE), Asb[BUF] + aL1o); \
    load_lds16(bG0 + (KE), Bsb[BUF] + bL0o); load_lds16(bG1 + (KE), Bsb[BUF] + bL1o); }

#define COMP2(BUF) { \
_Pragma("unroll") \
    for (int kk = 0; kk < 2; ++kk) { \
      bf16x8 av[4], bv[4]; \
_Pragma("unroll") \
      for (int mi = 0; mi < 4; ++mi) av[mi] = *(const bf16x8*)(Asb[BUF] + aoff[mi] + koff[kk]); \
_Pragma("unroll") \
      for (int ni = 0; ni < 4; ++ni) bv[ni] = *(const bf16x8*)(Bsb[BUF] + boff[ni] + koff[kk]); \
_Pragma("unroll") \
      for (int mi = 0; mi < 4; ++mi) \
_Pragma("unroll") \
        for (int ni = 0; ni < 4; ++ni) \
          acc[mi][ni] = MFMA16(av[mi], bv[ni], acc[mi][ni]); \
    } }

  STAGE2(0, 0)
  STAGE2(64, 1)
#pragma unroll 1
  for (int t = 0; t < 7; ++t) {
    const int ke = t * 128;
    WBAR(4); COMP2(0) BARO; STAGE2(ke + 128, 0)
    WBAR(4); COMP2(1) BARO; STAGE2(ke + 192, 1)
  }
  WBAR(4); COMP2(0)
  WBAR(0); COMP2(1)
#undef STAGE2
#undef COMP2

#pragma unroll
  for (int mi = 0; mi < 4; ++mi) {
#pragma unroll
    for (int r = 0; r < 4; ++r) {
      const int row = wrow + mi * 16 + quad * 4 + r;
      const bool rowok = row < rows;
      float ssum = 0.f;
#pragma unroll
      for (int ni = 0; ni < 4; ++ni) {
        const float v = acc[mi][ni][r];
        const int n = n0 + wcol + ni * 16 + lrow;
        const bool ok = rowok && (n < 1023);
        if (ok) obuf[(size_t)(mbase + row) * 1024 + n] = v;
        ssum += ok ? v * v : 0.f;
      }
      ssum += __shfl_xor(ssum, 1);
      ssum += __shfl_xor(ssum, 2);
      ssum += __shfl_xor(ssum, 4);
      ssum += __shfl_xor(ssum, 8);
      if (lrow == 0 && rowok) atomicAdd(ssbuf + mbase + row, ssum);
    }
  }
}

// ---------------- final LResNet combine + Lorentz normalize ----------------
__global__ __launch_bounds__(256) void combine_kernel(
    const float* __restrict__ o_r, const float* __restrict__ o_s,
    const float* __restrict__ ss_or, const float* __restrict__ ss_oz,
    const int* __restrict__ pos_of, const float* __restrict__ wgt,
    float* __restrict__ out)
{
  const int t = blockIdx.x, tid = threadIdx.x;
  const int p = pos_of[t];
  const float w = wgt[t];
  const float4 oz = ((const float4*)(o_s + (size_t)t * 1024))[tid];
  const float4 oe = ((const float4*)(o_r + (size_t)p * 1024))[tid];
  const float tw = 2.f * w;
  float c0 = oz.x + tw * oe.x;
  float c1 = oz.y + tw * oe.y;
  float c2 = oz.z + tw * oe.z;
  float c3 = (tid == 255) ? 0.f : (oz.w + tw * oe.w);  // n=1023 is padding
  float ssum = c0 * c0 + c1 * c1 + c2 * c2 + c3 * c3;
#pragma unroll
  for (int off = 32; off > 0; off >>= 1) ssum += __shfl_down(ssum, off);
  __shared__ float rs[4];
  if ((tid & 63) == 0) rs[tid >> 6] = ssum;
  __syncthreads();
  const float space2 = rs[0] + rs[1] + rs[2] + rs[3];
  const float comb0 = sqrtf(ss_oz[t] + 1.f) + 2.f + 2.f * w * sqrtf(ss_or[p] + 1.f);
  const float li = space2 - comb0 * comb0;
  const float inv = 1.f / sqrtf(fmaxf(fabsf(li), 1e-8f));
  float* orow = out + (size_t)t * 1024;
  const int j = 1 + tid * 4;
  orow[j]     = c0 * inv;
  orow[j + 1] = c1 * inv;
  orow[j + 2] = c2 * inv;
  if (tid != 255) orow[j + 3] = c3 * inv;
  if (tid == 0) orow[0] = comb0 * inv;
}

extern "C" void kernel_launch(void* const* d_in, const int* in_sizes, int n_in,
                              void* d_out, int out_size, void* d_ws, size_t ws_size,
                              hipStream_t stream) {
  const float* x      = (const float*)d_in[0];
  const float* gate_w = (const float*)d_in[1];
  const float* gate_b = (const float*)d_in[2];
  const float* W1     = (const float*)d_in[3];
  const float* W3     = (const float*)d_in[4];
  const float* W2     = (const float*)d_in[5];
  const float* Ws1    = (const float*)d_in[6];
  const float* Ws3    = (const float*)d_in[7];
  const float* Ws2    = (const float*)d_in[8];
  float* out = (float*)d_out;

  char* ws = (char*)d_ws;
  size_t off = 0;
  auto alloc = [&](size_t bytes) {
    void* p = ws + off;
    off += (bytes + 255) & ~(size_t)255;
    return p;
  };
  bf16*  x_bf = (bf16*) alloc((size_t)TOK * 1024 * 2);
  bf16*  h_r  = (bf16*) alloc((size_t)TOK * 1024 * 2);
  bf16*  h_s  = (bf16*) alloc((size_t)TOK * 1024 * 2);
  float* o_r  = (float*)alloc((size_t)TOK * 1024 * 4);
  float* o_s  = (float*)alloc((size_t)TOK * 1024 * 4);
  float* ss   = (float*)alloc((size_t)4 * TOK * 4);
  int*   eidx = (int*)  alloc((size_t)TOK * 4);
  float* ewgt = (float*)alloc((size_t)TOK * 4);
  int*   perm = (int*)  alloc((size_t)TOK * 4);
  int*   posf = (int*)  alloc((size_t)TOK * 4);
  int4*  wl1  = (int4*) alloc((size_t)SMAX * 16);
  int*   wn   = (int*)  alloc(32);
  bf16*  w13  = (bf16*) alloc((size_t)8 * 2046 * 1024 * 2);
  bf16*  ws13 = (bf16*) alloc((size_t)2046 * 1024 * 2);
  bf16*  w2b  = (bf16*) alloc((size_t)8 * 1023 * 1024 * 2);
  bf16*  ws2b = (bf16*) alloc((size_t)1023 * 1024 * 2);

  float* ss_r  = ss;
  float* ss_z  = ss + TOK;
  float* ss_or = ss + 2 * TOK;
  float* ss_oz = ss + 3 * TOK;

  // both MLP kernels use 128KB dynamic LDS (dbuf 256x64 A + 256x64 B)
  const int MLP_LDS = 2 * (256 * 64 + 256 * 64) * 2;  // 131072 B
  (void)hipFuncSetAttribute((const void*)mlp1_kernel,
                            hipFuncAttributeMaxDynamicSharedMemorySize, MLP_LDS);
  (void)hipFuncSetAttribute((const void*)mlp2_kernel,
                            hipFuncAttributeMaxDynamicSharedMemorySize, MLP_LDS);

  convert_kernel<<<NCVT, 128, 0, stream>>>(W1, W3, W2, Ws1, Ws3, Ws2,
                                           w13, ws13, w2b, ws2b);
  gate_cvt_kernel<<<TOK, 256, 0, stream>>>(x, gate_w, gate_b, x_bf, eidx, ewgt, ss);
  route_kernel<<<1, 256, 0, stream>>>(eidx, perm, posf, wl1, wn);
  mlp1_kernel<<<8 * SMAX, 1024, MLP_LDS, stream>>>(x_bf, w13, ws13, perm, wl1, wn,
                                                   h_r, h_s, ss_r, ss_z);
  finalize_t_kernel<<<8, 256, 0, stream>>>(ss_r, ss_z, h_r, h_s);
  mlp2_kernel<<<4 * SMAX, 1024, MLP_LDS, stream>>>(h_r, h_s, w2b, ws2b, wl1, wn,
                                                   o_r, o_s, ss_or, ss_oz);
  combine_kernel<<<TOK, 256, 0, stream>>>(o_r, o_s, ss_or, ss_oz, posf, ewgt, out);
}